// Round 5
// baseline (74.319 us; speedup 1.0000x reference)
//
#include <hip/hip_runtime.h>

// Gaussian splat renderer: B=2, 9 params x 32x32 gaussians -> [B,3,128,128].
//
// HALF-SET register-resident kernel. Rounds 0-4 evidence:
//   - feed-in-loop designs are pipe-bound: SMEM ~28us, LDS-broadcast ~26us
//   - full-set register design (144 VGPR rec) ran ~33us == L2-scratch model
//     => rec spilled; sched_barrier didn't help (regalloc, not scheduling)
//   - pure VALU floor ~5us
// Fix: each wave holds HALF the gaussians (4 pair-records/lane = 72 VGPRs,
// total demand ~120 regs -> no spill possible at the 256 cap, and ~4
// waves/SIMD for latency hiding). Two waves team up per 16-pixel set and
// combine partials via a 1KB LDS buffer once per pixel. Per-term math is
// identical to the passing round-3 kernel.
//
// Block = 256 thr = 2 pixel-sets x 2 half-waves; grid = 1024 blocks
// (4 blocks/CU). Per-pixel cross-lane sums via DPP (VALU pipe).

#define NB   2
#define NG   1024
#define HOUT 128
#define WOUT 128
#define NPW  16              // pixels per wave

typedef float v2f __attribute__((ext_vector_type(2)));

__device__ __forceinline__ float fast_exp(float x) {
    return __builtin_amdgcn_exp2f(x * 1.4426950408889634f);
}
__device__ __forceinline__ float fast_sigmoid(float x) {
    float e = __builtin_amdgcn_exp2f(-x * 1.4426950408889634f);
    return __builtin_amdgcn_rcpf(1.0f + e);
}
__device__ __forceinline__ float fast_tanh(float x) {
    float e = __builtin_amdgcn_exp2f(-x * 2.8853900817779268f);
    return fmaf(2.0f, __builtin_amdgcn_rcpf(1.0f + e), -1.0f);
}

// v += dpp(v); bound_ctrl=true zero-fills invalid lanes; masked-off rows keep
// old=0 so the add is a no-op there. All-VALU wave64 reduction.
template<int CTRL, int RM>
__device__ __forceinline__ float dpp_add(float v) {
    int s = __builtin_amdgcn_update_dpp(0, __float_as_int(v), CTRL, RM, 0xF, true);
    return v + __int_as_float(s);
}
// Full 64-lane sum; total lands in lane 63.
__device__ __forceinline__ float wave_sum(float v) {
    v = dpp_add<0x111, 0xF>(v);   // row_shr:1
    v = dpp_add<0x112, 0xF>(v);   // row_shr:2
    v = dpp_add<0x114, 0xF>(v);   // row_shr:4
    v = dpp_add<0x118, 0xF>(v);   // row_shr:8  -> row sums in lanes 15/31/47/63
    v = dpp_add<0x142, 0xA>(v);   // row_bcast15 -> lanes 31,63 = half sums
    v = dpp_add<0x143, 0xC>(v);   // row_bcast31 -> lane 63 = total
    return v;
}

// scalar covariance -> exp2-folded quadratic coefficients (by value)
struct Coefs { float A, B2, C; };
__device__ __forceinline__ Coefs cov_coefs(float p2, float p3, float p4) {
    float ea  = fast_exp(p2);
    float ec  = fast_exp(p4);
    float c00 = ea * ea + 1e-5f;
    float c01 = p3 * ea;
    float c11 = p3 * p3 + ec * ec + 1e-5f;
    float det = c00 * c11 - c01 * c01;
    float id  = 1.0f / det;            // exact divide: det can be ~1e-10
    const float s = -0.72134752044448169f;   // -0.5 * log2(e)
    Coefs r;
    r.A  = s * c11 * id;
    r.B2 = -2.0f * s * c01 * id;
    r.C  = s * c00 * id;
    return r;
}

__global__ __launch_bounds__(256, 2) void gauss_half(const float* __restrict__ params,
                                                     float* __restrict__ out) {
    __shared__ float4 sred[4][NPW];             // 1 KB partials

    const int tid  = threadIdx.x;
    const int lane = tid & 63;
    const int wv   = tid >> 6;                  // wave in block [0,4)
    const int ps   = wv >> 1;                   // pixel-set in block {0,1}
    const int half = wv & 1;                    // gaussian half {0,1}
    const int blk  = blockIdx.x;
    const int b    = blk >> 9;                  // 512 blocks per batch
    const int pixb = ((blk & 511) << 5);        // 32 px per block
    const int pix0 = pixb + ps * NPW;           // this wave's 16-px set

    // ---- prologue: lane holds pair-records n0 = half*512 + 2*lane + 128k --
    // rec[k]: {mux2, muy2, A2, B22, C2, op2, ocr2, ocg2, ocb2} (v2f = pair)
    v2f rec[4][9];
    const float* P = params + b * 9 * NG;       // channel stride = 1024
    #pragma unroll
    for (int k = 0; k < 4; ++k) {
        const int n0 = half * 512 + 2 * lane + 128 * k;  // even pair base
        v2f p[9];
        #pragma unroll
        for (int f = 0; f < 9; ++f)
            p[f] = *(const v2f*)(P + f * NG + n0);   // coalesced 8B loads

        // base_grid: -0.96875 + i/16; tanh offset * (2/32)
        const float gw = (float)(n0 & 31);      // even, <=30 -> no row wrap
        const float gh = (float)(n0 >> 5);
        v2f mux2, muy2, A2, B22, C2;
        mux2.x = -0.96875f + gw * 0.0625f + fast_tanh(p[0].x) * 0.0625f;
        mux2.y = -0.96875f + (gw + 1.0f) * 0.0625f + fast_tanh(p[0].y) * 0.0625f;
        muy2.x = -0.96875f + gh * 0.0625f + fast_tanh(p[1].x) * 0.0625f;
        muy2.y = -0.96875f + gh * 0.0625f + fast_tanh(p[1].y) * 0.0625f;
        Coefs cx = cov_coefs(p[2].x, p[3].x, p[4].x);
        Coefs cy = cov_coefs(p[2].y, p[3].y, p[4].y);
        A2.x = cx.A; B22.x = cx.B2; C2.x = cx.C;
        A2.y = cy.A; B22.y = cy.B2; C2.y = cy.C;
        v2f op2, ocr2, ocg2, ocb2;
        op2.x  = fast_sigmoid(p[8].x);         op2.y  = fast_sigmoid(p[8].y);
        ocr2.x = op2.x * fast_sigmoid(p[5].x); ocr2.y = op2.y * fast_sigmoid(p[5].y);
        ocg2.x = op2.x * fast_sigmoid(p[6].x); ocg2.y = op2.y * fast_sigmoid(p[6].y);
        ocb2.x = op2.x * fast_sigmoid(p[7].x); ocb2.y = op2.y * fast_sigmoid(p[7].y);

        rec[k][0] = mux2; rec[k][1] = muy2; rec[k][2] = A2;
        rec[k][3] = B22;  rec[k][4] = C2;   rec[k][5] = op2;
        rec[k][6] = ocr2; rec[k][7] = ocg2; rec[k][8] = ocb2;
    }

    // ---- render: 16 pixels, this wave's 512 gaussians, no memory in loop --
    const int w0 = pix0 & 127;                  // pix0 multiple of 16 -> one row
    const int h0 = pix0 >> 7;
    const float py = -1.0f + (float)h0 * (2.0f / 127.0f);
    const v2f py2 = {py, py};

    #pragma unroll 2
    for (int i = 0; i < NPW; ++i) {
        const float px = -1.0f + (float)(w0 + i) * (2.0f / 127.0f);
        const v2f px2 = {px, px};
        v2f wsum2 = {0.0f, 0.0f}, ar2 = {0.0f, 0.0f};
        v2f ag2   = {0.0f, 0.0f}, ab2 = {0.0f, 0.0f};

        #pragma unroll
        for (int k = 0; k < 4; ++k) {
            v2f dx = px2 - rec[k][0];
            v2f dy = py2 - rec[k][1];
            v2f m  = rec[k][2] * dx;
            m      = __builtin_elementwise_fma(rec[k][3], dy, m);
            v2f t  = rec[k][4] * dy;
            v2f e2 = __builtin_elementwise_fma(t, dy, m * dx);
            e2 = __builtin_elementwise_max(e2, (v2f){-28.853900817779268f,
                                                     -28.853900817779268f});
            v2f k2 = {__builtin_amdgcn_exp2f(e2.x), __builtin_amdgcn_exp2f(e2.y)};
            wsum2 = __builtin_elementwise_fma(rec[k][5], k2, wsum2);
            ar2   = __builtin_elementwise_fma(rec[k][6], k2, ar2);
            ag2   = __builtin_elementwise_fma(rec[k][7], k2, ag2);
            ab2   = __builtin_elementwise_fma(rec[k][8], k2, ab2);
        }

        float ws = wave_sum(wsum2.x + wsum2.y);
        float rr = wave_sum(ar2.x + ar2.y);
        float gg = wave_sum(ag2.x + ag2.y);
        float bb = wave_sum(ab2.x + ab2.y);
        if (lane == 63) sred[wv][i] = make_float4(ws, rr, gg, bb);
    }
    __syncthreads();

    // ---- combine the two halves, normalize, store (32 px per block) -------
    if (tid < 32) {
        const int cps = tid >> 4;               // pixel-set
        const int i   = tid & 15;               // pixel in set
        float4 a = sred[cps * 2][i];
        float4 c = sred[cps * 2 + 1][i];
        float ws = a.x + c.x, rr = a.y + c.y, gg = a.z + c.z, bb = a.w + c.w;
        float inv = 1.0f / (ws + 1e-8f);
        const int pix = pixb + cps * NPW + i;
        float* ob = out + b * 3 * (HOUT * WOUT) + pix;
        ob[0]               = rr * inv;
        ob[HOUT * WOUT]     = gg * inv;
        ob[2 * HOUT * WOUT] = bb * inv;
    }
}

extern "C" void kernel_launch(void* const* d_in, const int* in_sizes, int n_in,
                              void* d_out, int out_size, void* d_ws, size_t ws_size,
                              hipStream_t stream) {
    const float* params = (const float*)d_in[0];
    float* out = (float*)d_out;
    (void)d_ws; (void)ws_size;   // workspace intentionally unused

    // 2 batches * 16384 px / (32 px per block) = 1024 blocks
    hipLaunchKernelGGL(gauss_half, dim3(1024), dim3(256), 0, stream, params, out);
}

// Round 6
// 66.151 us; speedup vs baseline: 1.1235x; 1.1235x over previous
//
#include <hip/hip_runtime.h>

// Gaussian splat renderer: B=2, 9 params x 32x32 gaussians -> [B,3,128,128].
//
// Fused LDS-broadcast kernel with 2 PIXELS PER LANE. Rounds 0-5 established:
//  - the render loop is LDS-BANDWIDTH bound: wave-uniform broadcast reads
//    still deliver 64 lanes x 72 B per record per wave. r1 (1 px/lane):
//    8192 waves x 32 iters x 4608 B = 1.21 GB @ ~69 TB/s = ~17.5us == obs.
//  - register-resident variants (r3-r5) were WORSE (~34us): fewer waves,
//    serial DPP reduce chains, prologue latency; spilling was refuted (r5).
//  - harness overhead (256MiB poison fill ~39.6us + reset dispatches) is a
//    fixed floor we cannot touch.
// This version keeps the proven r1 structure but each lane accumulates TWO
// pixels of the same image row per record read -> LDS bytes halve (~8.8us),
// and the dy-dependent terms (dy, B2*dy, C*dy^2) are CSE'd across the two
// pixels so VALU stays ~4.7us/SIMD (still LDS-bound). 128 px/block ->
// 256 blocks = exactly 1 block/CU (one table build per CU instead of two).
//
// blockDim = (64 px-lanes, 16 chunks) = 1024 thr. LDS = 40KB table + 32KB
// reduce = 72KB -> 1 block/CU, 4 waves/SIMD.

#define NB   2
#define NG   1024            // gaussians per batch (32*32)
#define HOUT 128
#define WOUT 128
#define PSTRIDE 20           // floats per gaussian-PAIR record (18 used + pad)
#define NCHUNK 16

typedef float v2f __attribute__((ext_vector_type(2)));

__device__ __forceinline__ float fast_exp(float x) {
    return __builtin_amdgcn_exp2f(x * 1.4426950408889634f);
}
__device__ __forceinline__ float fast_sigmoid(float x) {
    float e = __builtin_amdgcn_exp2f(-x * 1.4426950408889634f);
    return __builtin_amdgcn_rcpf(1.0f + e);
}
__device__ __forceinline__ float fast_tanh(float x) {
    float e = __builtin_amdgcn_exp2f(-x * 2.8853900817779268f);
    return fmaf(2.0f, __builtin_amdgcn_rcpf(1.0f + e), -1.0f);
}

__global__ __launch_bounds__(1024) void gauss_fused(const float* __restrict__ params,
                                                    float* __restrict__ out) {
    __shared__ __align__(16) float gtab[(NG / 2) * PSTRIDE];  // 40 KB
    __shared__ float4 sred[NCHUNK][128];                      // 32 KB partials

    const int tx  = threadIdx.x;             // pixel lane   [0,64)
    const int ty  = threadIdx.y;             // chunk        [0,16)
    const int tid = ty * 64 + tx;
    const int blk = blockIdx.x;
    const int b   = blk >> 7;                // 128 blocks (rows) per batch
    const int row = blk & 127;               // image row
    const int pixb = row << 7;               // first pixel of this row

    // ---------------- per-gaussian setup: thread tid -> gaussian tid -------
    {
        const int n = tid;
        const int gh = n >> 5;
        const int gw = n & 31;

        const float* P = params + b * 9 * NG + n;   // channel stride = 1024
        float p0 = P[0 * NG];
        float p1 = P[1 * NG];
        float p2 = P[2 * NG];
        float p3 = P[3 * NG];
        float p4 = P[4 * NG];
        float p5 = P[5 * NG];
        float p6 = P[6 * NG];
        float p7 = P[7 * NG];
        float p8 = P[8 * NG];

        // base_grid: linspace(-31/32, 31/32, 32) -> -0.96875 + i/16; off 2/32
        float mux = -0.96875f + (float)gw * 0.0625f + fast_tanh(p0) * 0.0625f;
        float muy = -0.96875f + (float)gh * 0.0625f + fast_tanh(p1) * 0.0625f;

        // cov = L L^T + 1e-5 I,  L = [[e^a,0],[b,e^c]]
        float ea  = fast_exp(p2);
        float ec  = fast_exp(p4);
        float c00 = ea * ea + 1e-5f;
        float c01 = p3 * ea;
        float c11 = p3 * p3 + ec * ec + 1e-5f;
        float det = c00 * c11 - c01 * c01;
        float id  = 1.0f / det;            // exact divide: det can be ~1e-10
        float Sa  =  c11 * id;
        float Sb  = -c01 * id;
        float Sc  =  c00 * id;

        // fold -0.5*log2(e) so the render loop computes exp2 directly
        const float s = -0.72134752044448169f;   // -0.5 * log2(e)
        float A  = s * Sa;
        float B2 = 2.0f * s * Sb;
        float C  = s * Sc;

        float cr = fast_sigmoid(p5);
        float cg = fast_sigmoid(p6);
        float cb = fast_sigmoid(p7);
        float op = fast_sigmoid(p8);

        // pair-blocked layout: record (n>>1), half (n&1); field stride 2
        float* o = gtab + (n >> 1) * PSTRIDE + (n & 1);
        o[0]  = mux;  o[2]  = muy;  o[4]  = A;       o[6]  = B2;
        o[8]  = C;    o[10] = op;   o[12] = op * cr; o[14] = op * cg;
        o[16] = op * cb;
    }
    __syncthreads();

    // ---------------- render: 2 pixels per lane, same row ------------------
    const float py  = -1.0f + (float)row * (2.0f / 127.0f);
    const float pxA = -1.0f + (float)tx * (2.0f / 127.0f);
    const float pxB = -1.0f + (float)(tx + 64) * (2.0f / 127.0f);
    const v2f py2  = {py, py};
    const v2f pxA2 = {pxA, pxA};
    const v2f pxB2 = {pxB, pxB};

    // wave-uniform chunk base; uniform-address LDS reads broadcast.
    const v2f* __restrict__ gp =
        (const v2f*)(gtab + ty * (NG / 2 / NCHUNK) * PSTRIDE);

    v2f wsA = {0,0}, arA = {0,0}, agA = {0,0}, abA = {0,0};
    v2f wsB = {0,0}, arB = {0,0}, agB = {0,0}, abB = {0,0};

    #pragma unroll 4
    for (int j = 0; j < NG / 2 / NCHUNK; ++j) {     // 32 pair-iterations
        const v2f* __restrict__ r = gp + j * (PSTRIDE / 2);
        v2f mux2 = r[0], muy2 = r[1];
        v2f A2   = r[2], B22  = r[3], C2 = r[4];
        v2f op2  = r[5], ocr2 = r[6], ocg2 = r[7], ocb2 = r[8];

        // shared across the two pixels (same row => same dy)
        v2f dy   = py2 - muy2;
        v2f bdy  = B22 * dy;
        v2f cdy2 = (C2 * dy) * dy;
        const v2f clampv = {-28.853900817779268f, -28.853900817779268f};

        // pixel A
        v2f dxA = pxA2 - mux2;
        v2f eA  = __builtin_elementwise_fma(
                      dxA, __builtin_elementwise_fma(A2, dxA, bdy), cdy2);
        eA = __builtin_elementwise_max(eA, clampv);
        v2f kA = {__builtin_amdgcn_exp2f(eA.x), __builtin_amdgcn_exp2f(eA.y)};
        wsA = __builtin_elementwise_fma(op2,  kA, wsA);
        arA = __builtin_elementwise_fma(ocr2, kA, arA);
        agA = __builtin_elementwise_fma(ocg2, kA, agA);
        abA = __builtin_elementwise_fma(ocb2, kA, abA);

        // pixel B
        v2f dxB = pxB2 - mux2;
        v2f eB  = __builtin_elementwise_fma(
                      dxB, __builtin_elementwise_fma(A2, dxB, bdy), cdy2);
        eB = __builtin_elementwise_max(eB, clampv);
        v2f kB = {__builtin_amdgcn_exp2f(eB.x), __builtin_amdgcn_exp2f(eB.y)};
        wsB = __builtin_elementwise_fma(op2,  kB, wsB);
        arB = __builtin_elementwise_fma(ocr2, kB, arB);
        agB = __builtin_elementwise_fma(ocg2, kB, agB);
        abB = __builtin_elementwise_fma(ocb2, kB, abB);
    }

    sred[ty][tx]      = make_float4(wsA.x + wsA.y, arA.x + arA.y,
                                    agA.x + agA.y, abA.x + abA.y);
    sred[ty][tx + 64] = make_float4(wsB.x + wsB.y, arB.x + arB.y,
                                    agB.x + agB.y, abB.x + abB.y);
    __syncthreads();

    // ---------------- combine chunks, normalize, store (128 px/block) ------
    if (tid < 128) {
        float4 a = sred[0][tid];
        #pragma unroll
        for (int c = 1; c < NCHUNK; ++c) {
            float4 t = sred[c][tid];
            a.x += t.x; a.y += t.y; a.z += t.z; a.w += t.w;
        }
        float inv = 1.0f / (a.x + 1e-8f);
        float* ob = out + b * 3 * (HOUT * WOUT) + pixb + tid;
        ob[0]               = a.y * inv;
        ob[HOUT * WOUT]     = a.z * inv;
        ob[2 * HOUT * WOUT] = a.w * inv;
    }
}

extern "C" void kernel_launch(void* const* d_in, const int* in_sizes, int n_in,
                              void* d_out, int out_size, void* d_ws, size_t ws_size,
                              hipStream_t stream) {
    const float* params = (const float*)d_in[0];
    float* out = (float*)d_out;
    (void)d_ws; (void)ws_size;   // workspace intentionally unused

    // 2 batches * 128 rows = 256 blocks (1 per CU), 1024 threads each
    hipLaunchKernelGGL(gauss_fused, dim3(NB * 128), dim3(64, NCHUNK), 0, stream,
                       params, out);
}